// Round 10
// baseline (331.305 us; speedup 1.0000x reference)
//
#include <hip/hip_runtime.h>

#define TT 52          // tag count incl START/STOP
#define NT 50          // normal tags
#define START_TAG 50
#define STOP_TAG 51
#define BB 1024
#define SS 512
#define BPSTR 64       // fallback kernel LDS bp row stride

__device__ __forceinline__ int seq_len(const void* mask, int b, int j) {
    int cnt = 0;
    const unsigned* w = (const unsigned*)mask;
    unsigned w0 = w[0];
    unsigned w1 = w[1];
    if (w0 == 0x01010101u) {                       // bool / uint8
        const unsigned char* m = (const unsigned char*)mask + (size_t)b * SS;
        for (int k = j; k < SS; k += 64) cnt += (m[k] != 0);
    } else if (w0 == 0x3f800000u) {                // float32
        const float* m = (const float*)mask + (size_t)b * SS;
        for (int k = j; k < SS; k += 64) cnt += (m[k] != 0.f);
    } else if (w1 == 1u) {                         // int32
        const int* m = (const int*)mask + (size_t)b * SS;
        for (int k = j; k < SS; k += 64) cnt += (m[k] != 0);
    } else {                                       // int64
        const long long* m = (const long long*)mask + (size_t)b * SS;
        for (int k = j; k < SS; k += 64) cnt += (m[k] != 0);
    }
    for (int off = 32; off; off >>= 1) cnt += __shfl_xor(cnt, off, 64);
    return cnt > 0 ? cnt : 1;
}

// One DP step (textual macro; ambient: j, tt[NT]):
// LDS broadcast (1 ds_write + 13 broadcast ds_read_b128), add tt, exact max3
// tree, store bv to WSB, ALPHA = bv + FREG. Bit-identical math to reference.
#define DP_STEP(ALPHA, ABUF, WSB, FREG, POSV)                                     \
    {                                                                             \
        (ABUF)[j] = ALPHA;                                                        \
        float q_[52];                                                             \
        _Pragma("unroll")                                                         \
        for (int r_ = 0; r_ < 13; ++r_) {                                         \
            float4 t4_ = ((const float4*)(ABUF))[r_];                             \
            q_[4 * r_ + 0] = t4_.x; q_[4 * r_ + 1] = t4_.y;                       \
            q_[4 * r_ + 2] = t4_.z; q_[4 * r_ + 3] = t4_.w;                       \
        }                                                                         \
        float s_[NT];                                                             \
        _Pragma("unroll")                                                         \
        for (int i_ = 0; i_ < NT; ++i_) s_[i_] = q_[i_] + tt[i_];                 \
        float m_[17];                                                             \
        _Pragma("unroll")                                                         \
        for (int k_ = 0; k_ < 16; ++k_)                                           \
            m_[k_] = fmaxf(fmaxf(s_[3 * k_], s_[3 * k_ + 1]), s_[3 * k_ + 2]);    \
        m_[16] = fmaxf(s_[48], s_[49]);                                           \
        float n_[6];                                                              \
        _Pragma("unroll")                                                         \
        for (int k_ = 0; k_ < 5; ++k_)                                            \
            n_[k_] = fmaxf(fmaxf(m_[3 * k_], m_[3 * k_ + 1]), m_[3 * k_ + 2]);    \
        n_[5] = fmaxf(m_[15], m_[16]);                                            \
        float q0_ = fmaxf(fmaxf(n_[0], n_[1]), n_[2]);                            \
        float q1_ = fmaxf(fmaxf(n_[3], n_[4]), n_[5]);                            \
        float bv_ = fmaxf(q0_, q1_);                                              \
        (WSB)[(size_t)(POSV) * 64] = bv_;                                         \
        ALPHA = bv_ + (FREG);                                                     \
    }

// generic value-match traceback step (ambient: j, jc, jr, trans_lds)
#define TB_STEP_G(PTR, TPOS, BVC, BVS, FS, OB, WSR, FB, K)                        \
    {                                                                             \
        float bvp_ = BVS[K];                                                      \
        float ap_ = bvp_ + FS[K];                                                 \
        float cand_ = ap_ + trans_lds[jr + PTR];                                  \
        float cm_ = (j < NT) ? cand_ : -3.0e38f;                                  \
        float tgt_ = __builtin_bit_cast(float,                                    \
            __builtin_amdgcn_readlane(__builtin_bit_cast(int, BVC), PTR));        \
        unsigned long long bm_ = __ballot(cm_ == tgt_);                           \
        PTR = __ffsll(bm_) - 1;                                                   \
        --TPOS;                                                                   \
        OB[TPOS] = PTR;                                                           \
        BVC = bvp_;                                                               \
        int rc_ = TPOS - 4; rc_ = rc_ < 0 ? 0 : rc_;                              \
        BVS[K] = WSR[(size_t)rc_ * 64 + j];                                       \
        FS[K] = FB[(size_t)rc_ * TT + jc];                                        \
    }

// ---------------- prep kernel 1: per-batch length -----------------------
__global__ __launch_bounds__(64, 1) void crf_lens(
    const void* __restrict__ mask, int* __restrict__ lens_g)
{
    int len = seq_len(mask, blockIdx.x, threadIdx.x);
    if (threadIdx.x == 0) lens_g[blockIdx.x] = len;
}

// ---------------- prep kernel 2: counting-sort rank -> perm --------------
__global__ __launch_bounds__(1024, 1) void crf_rank(
    const int* __restrict__ lens_g, int* __restrict__ perm)
{
    __shared__ int hist[SS + 1];
    const int t = threadIdx.x;
    if (t <= SS) hist[t] = 0;
    __syncthreads();
    const int myl = lens_g[t];          // 1..512
    atomicAdd(&hist[myl], 1);
    __syncthreads();
    if (t == 0) {
        int acc = 0;
        for (int k = 0; k <= SS; ++k) { int h = hist[k]; hist[k] = acc; acc += h; }
    }
    __syncthreads();
    int r = atomicAdd(&hist[myl], 1);   // slot within bucket
    perm[r] = t;                        // perm sorted ascending by length
}

// ---------------- main kernel: 2 length-matched chains per wave ----------
__global__ __launch_bounds__(64, 1) void crf_viterbi_fast2(
    const float* __restrict__ feats,   // [B,S,T]
    const float* __restrict__ trans,   // [T,T]
    const int*  __restrict__ lens_g,   // [B]
    const int*  __restrict__ perm,     // [B] sorted by length
    float* __restrict__ ws,            // [B,S,64] bv history
    int* __restrict__ out)             // [B,S]
{
    __shared__ float trans_lds[64 * 53];
    __shared__ __align__(16) float a_sh0[2][64];
    __shared__ __align__(16) float a_sh1[2][64];

    const int bid = blockIdx.x;
    const int j = threadIdx.x;
    const int jc = j < NT ? j : NT - 1;
    const int jr = j * 53;

    const int b0 = perm[2 * bid];
    const int b1 = perm[2 * bid + 1];
    const int len0 = lens_g[b0];
    const int len1 = lens_g[b1];
    const int lmin = len0 < len1 ? len0 : len1;

    for (int k = j; k < 64 * 53; k += 64) {
        int r = k / 53, c = k - r * 53;
        float v = -3.0e38f;
        if (r < NT && c < TT) v = trans[r * TT + c];
        trans_lds[k] = v;
    }

    float tt[NT];
#pragma unroll
    for (int i = 0; i < NT; ++i) tt[i] = trans[i * TT + j];

    const float* fp0 = feats + ((size_t)b0 * SS) * TT + jc;
    const float* fp1 = feats + ((size_t)b1 * SS) * TT + jc;
    float* wsb0 = ws + ((size_t)b0 * SS) * 64 + j;
    float* wsb1 = ws + ((size_t)b1 * SS) * 64 + j;

    const float bvi = trans[START_TAG * TT + jc];
    float alpha0 = bvi + fp0[0];
    float alpha1 = bvi + fp1[0];
    wsb0[0] = bvi;
    wsb1[0] = bvi;

#define FLD0(P) fp0[(size_t)((P) < SS ? (P) : SS - 1) * TT]
#define FLD1(P) fp1[(size_t)((P) < SS ? (P) : SS - 1) * TT]

    // 8-deep feats prefetch per chain; invariant at loop top:
    // fA* = f[pos..pos+3], fB* = f[pos+4..pos+7]
    float fA00 = FLD0(1), fA01 = FLD0(2), fA02 = FLD0(3), fA03 = FLD0(4);
    float fB00 = FLD0(5), fB01 = FLD0(6), fB02 = FLD0(7), fB03 = FLD0(8);
    float fA10 = FLD1(1), fA11 = FLD1(2), fA12 = FLD1(3), fA13 = FLD1(4);
    float fB10 = FLD1(5), fB11 = FLD1(6), fB12 = FLD1(7), fB13 = FLD1(8);

    int pos = 1;
    for (; pos + 7 < lmin; pos += 8) {
        DP_STEP(alpha0, a_sh0[(pos + 0) & 1], wsb0, fA00, pos + 0)
        DP_STEP(alpha1, a_sh1[(pos + 0) & 1], wsb1, fA10, pos + 0)
        DP_STEP(alpha0, a_sh0[(pos + 1) & 1], wsb0, fA01, pos + 1)
        DP_STEP(alpha1, a_sh1[(pos + 1) & 1], wsb1, fA11, pos + 1)
        DP_STEP(alpha0, a_sh0[(pos + 2) & 1], wsb0, fA02, pos + 2)
        DP_STEP(alpha1, a_sh1[(pos + 2) & 1], wsb1, fA12, pos + 2)
        DP_STEP(alpha0, a_sh0[(pos + 3) & 1], wsb0, fA03, pos + 3)
        DP_STEP(alpha1, a_sh1[(pos + 3) & 1], wsb1, fA13, pos + 3)
        fA00 = FLD0(pos + 8);  fA01 = FLD0(pos + 9);
        fA02 = FLD0(pos + 10); fA03 = FLD0(pos + 11);
        fA10 = FLD1(pos + 8);  fA11 = FLD1(pos + 9);
        fA12 = FLD1(pos + 10); fA13 = FLD1(pos + 11);
        DP_STEP(alpha0, a_sh0[(pos + 4) & 1], wsb0, fB00, pos + 4)
        DP_STEP(alpha1, a_sh1[(pos + 4) & 1], wsb1, fB10, pos + 4)
        DP_STEP(alpha0, a_sh0[(pos + 5) & 1], wsb0, fB01, pos + 5)
        DP_STEP(alpha1, a_sh1[(pos + 5) & 1], wsb1, fB11, pos + 5)
        DP_STEP(alpha0, a_sh0[(pos + 6) & 1], wsb0, fB02, pos + 6)
        DP_STEP(alpha1, a_sh1[(pos + 6) & 1], wsb1, fB12, pos + 6)
        DP_STEP(alpha0, a_sh0[(pos + 7) & 1], wsb0, fB03, pos + 7)
        DP_STEP(alpha1, a_sh1[(pos + 7) & 1], wsb1, fB13, pos + 7)
        fB00 = FLD0(pos + 12); fB01 = FLD0(pos + 13);
        fB02 = FLD0(pos + 14); fB03 = FLD0(pos + 15);
        fB10 = FLD1(pos + 12); fB11 = FLD1(pos + 13);
        fB12 = FLD1(pos + 14); fB13 = FLD1(pos + 15);
    }
    // joint tail (<=7 steps), prefetch regs hold f[pos..pos+7]
    if (pos < lmin) { DP_STEP(alpha0, a_sh0[pos & 1], wsb0, fA00, pos)
                      DP_STEP(alpha1, a_sh1[pos & 1], wsb1, fA10, pos) ++pos; }
    if (pos < lmin) { DP_STEP(alpha0, a_sh0[pos & 1], wsb0, fA01, pos)
                      DP_STEP(alpha1, a_sh1[pos & 1], wsb1, fA11, pos) ++pos; }
    if (pos < lmin) { DP_STEP(alpha0, a_sh0[pos & 1], wsb0, fA02, pos)
                      DP_STEP(alpha1, a_sh1[pos & 1], wsb1, fA12, pos) ++pos; }
    if (pos < lmin) { DP_STEP(alpha0, a_sh0[pos & 1], wsb0, fA03, pos)
                      DP_STEP(alpha1, a_sh1[pos & 1], wsb1, fA13, pos) ++pos; }
    if (pos < lmin) { DP_STEP(alpha0, a_sh0[pos & 1], wsb0, fB00, pos)
                      DP_STEP(alpha1, a_sh1[pos & 1], wsb1, fB10, pos) ++pos; }
    if (pos < lmin) { DP_STEP(alpha0, a_sh0[pos & 1], wsb0, fB01, pos)
                      DP_STEP(alpha1, a_sh1[pos & 1], wsb1, fB11, pos) ++pos; }
    if (pos < lmin) { DP_STEP(alpha0, a_sh0[pos & 1], wsb0, fB02, pos)
                      DP_STEP(alpha1, a_sh1[pos & 1], wsb1, fB12, pos) ++pos; }

    // per-chain remainders (sorted pairing => tiny; direct loads)
    for (int p = pos; p < len0; ++p) {
        float f = fp0[(size_t)p * TT];
        DP_STEP(alpha0, a_sh0[p & 1], wsb0, f, p)
    }
    for (int p = pos; p < len1; ++p) {
        float f = fp1[(size_t)p * TT];
        DP_STEP(alpha1, a_sh1[p & 1], wsb1, f, p)
    }

    // ---- best last tag, both chains ----
    float v0 = alpha0 + trans[jc * TT + STOP_TAG];
    float v1 = alpha1 + trans[jc * TT + STOP_TAG];
    if (j >= NT) { v0 = -3.0e38f; v1 = -3.0e38f; }
    int idx0 = j < NT ? j : 0;
    int idx1 = idx0;
    for (int off = 32; off; off >>= 1) {
        float vo0 = __shfl_xor(v0, off, 64);
        int   io0 = __shfl_xor(idx0, off, 64);
        if (vo0 > v0 || (vo0 == v0 && io0 < idx0)) { v0 = vo0; idx0 = io0; }
        float vo1 = __shfl_xor(v1, off, 64);
        int   io1 = __shfl_xor(idx1, off, 64);
        if (vo1 > v1 || (vo1 == v1 && io1 < idx1)) { v1 = vo1; idx1 = io1; }
    }

    // ---- interleaved value-match tracebacks ----
    int ptr0 = idx0, ptr1 = idx1;
    int* ob0 = out + (size_t)b0 * SS;
    int* ob1 = out + (size_t)b1 * SS;
    ob0[len0 - 1] = ptr0;
    ob1[len1 - 1] = ptr1;

    const float* wsr0 = ws + ((size_t)b0 * SS) * 64;
    const float* wsr1 = ws + ((size_t)b1 * SS) * 64;
    const float* fb0 = feats + ((size_t)b0 * SS) * TT;
    const float* fb1 = feats + ((size_t)b1 * SS) * TT;

    float bvs0[4], fs0[4], bvs1[4], fs1[4];
    float bvc0 = wsr0[(size_t)(len0 - 1) * 64 + j];
    float bvc1 = wsr1[(size_t)(len1 - 1) * 64 + j];
#pragma unroll
    for (int k = 0; k < 4; ++k) {
        int r0 = len0 - 2 - k; int rc0 = r0 < 0 ? 0 : r0;
        bvs0[k] = wsr0[(size_t)rc0 * 64 + j];
        fs0[k]  = fb0[(size_t)rc0 * TT + jc];
        int r1 = len1 - 2 - k; int rc1 = r1 < 0 ? 0 : r1;
        bvs1[k] = wsr1[(size_t)rc1 * 64 + j];
        fs1[k]  = fb1[(size_t)rc1 * TT + jc];
    }

    int tpos0 = len0 - 1, tpos1 = len1 - 1;
    while (tpos0 >= 4 && tpos1 >= 4) {
        TB_STEP_G(ptr0, tpos0, bvc0, bvs0, fs0, ob0, wsr0, fb0, 0)
        TB_STEP_G(ptr1, tpos1, bvc1, bvs1, fs1, ob1, wsr1, fb1, 0)
        TB_STEP_G(ptr0, tpos0, bvc0, bvs0, fs0, ob0, wsr0, fb0, 1)
        TB_STEP_G(ptr1, tpos1, bvc1, bvs1, fs1, ob1, wsr1, fb1, 1)
        TB_STEP_G(ptr0, tpos0, bvc0, bvs0, fs0, ob0, wsr0, fb0, 2)
        TB_STEP_G(ptr1, tpos1, bvc1, bvs1, fs1, ob1, wsr1, fb1, 2)
        TB_STEP_G(ptr0, tpos0, bvc0, bvs0, fs0, ob0, wsr0, fb0, 3)
        TB_STEP_G(ptr1, tpos1, bvc1, bvs1, fs1, ob1, wsr1, fb1, 3)
    }
    while (tpos0 >= 4) {
        TB_STEP_G(ptr0, tpos0, bvc0, bvs0, fs0, ob0, wsr0, fb0, 0)
        TB_STEP_G(ptr0, tpos0, bvc0, bvs0, fs0, ob0, wsr0, fb0, 1)
        TB_STEP_G(ptr0, tpos0, bvc0, bvs0, fs0, ob0, wsr0, fb0, 2)
        TB_STEP_G(ptr0, tpos0, bvc0, bvs0, fs0, ob0, wsr0, fb0, 3)
    }
    while (tpos1 >= 4) {
        TB_STEP_G(ptr1, tpos1, bvc1, bvs1, fs1, ob1, wsr1, fb1, 0)
        TB_STEP_G(ptr1, tpos1, bvc1, bvs1, fs1, ob1, wsr1, fb1, 1)
        TB_STEP_G(ptr1, tpos1, bvc1, bvs1, fs1, ob1, wsr1, fb1, 2)
        TB_STEP_G(ptr1, tpos1, bvc1, bvs1, fs1, ob1, wsr1, fb1, 3)
    }
    if (tpos0 >= 1) TB_STEP_G(ptr0, tpos0, bvc0, bvs0, fs0, ob0, wsr0, fb0, 0)
    if (tpos0 >= 1) TB_STEP_G(ptr0, tpos0, bvc0, bvs0, fs0, ob0, wsr0, fb0, 1)
    if (tpos0 >= 1) TB_STEP_G(ptr0, tpos0, bvc0, bvs0, fs0, ob0, wsr0, fb0, 2)
    if (tpos1 >= 1) TB_STEP_G(ptr1, tpos1, bvc1, bvs1, fs1, ob1, wsr1, fb1, 0)
    if (tpos1 >= 1) TB_STEP_G(ptr1, tpos1, bvc1, bvs1, fs1, ob1, wsr1, fb1, 1)
    if (tpos1 >= 1) TB_STEP_G(ptr1, tpos1, bvc1, bvs1, fs1, ob1, wsr1, fb1, 2)

    // zero-fill positions >= len
    for (int p = len0 + j; p < SS; p += 64) ob0[p] = 0;
    for (int p = len1 + j; p < SS; p += 64) ob1[p] = 0;
#undef FLD0
#undef FLD1
}

// ---------------- round-9 single-chain kernel (middle ws branch) ------------
__global__ __launch_bounds__(64, 1) void crf_viterbi_fast1(
    const float* __restrict__ feats,
    const void*  __restrict__ mask,
    const float* __restrict__ trans,
    float* __restrict__ ws,
    int* __restrict__ out)
{
    __shared__ float trans_lds[64 * 53];
    __shared__ __align__(16) float a_sh[2][64];

    const int b = blockIdx.x;
    const int j = threadIdx.x;
    const int jc = j < NT ? j : NT - 1;
    const int jr = j * 53;

    for (int k = j; k < 64 * 53; k += 64) {
        int r = k / 53, c = k - r * 53;
        float v = -3.0e38f;
        if (r < NT && c < TT) v = trans[r * TT + c];
        trans_lds[k] = v;
    }

    const int len = seq_len(mask, b, j);

    float tt[NT];
#pragma unroll
    for (int i = 0; i < NT; ++i) tt[i] = trans[i * TT + j];

    const float* fp = feats + ((size_t)b * SS) * TT + jc;
    float* wsb = ws + ((size_t)b * SS) * 64 + j;
    const float bvi = trans[START_TAG * TT + jc];
    float alpha = bvi + fp[0];
    wsb[0] = bvi;

#define FLD(P) fp[(size_t)((P) < SS ? (P) : SS - 1) * TT]
    float fA0 = FLD(1), fA1 = FLD(2), fA2 = FLD(3), fA3 = FLD(4);
    float fB0 = FLD(5), fB1 = FLD(6), fB2 = FLD(7), fB3 = FLD(8);

    int pos = 1;
    for (; pos + 7 < len; pos += 8) {
        DP_STEP(alpha, a_sh[(pos + 0) & 1], wsb, fA0, pos + 0)
        DP_STEP(alpha, a_sh[(pos + 1) & 1], wsb, fA1, pos + 1)
        DP_STEP(alpha, a_sh[(pos + 2) & 1], wsb, fA2, pos + 2)
        DP_STEP(alpha, a_sh[(pos + 3) & 1], wsb, fA3, pos + 3)
        fA0 = FLD(pos + 8);  fA1 = FLD(pos + 9);
        fA2 = FLD(pos + 10); fA3 = FLD(pos + 11);
        DP_STEP(alpha, a_sh[(pos + 4) & 1], wsb, fB0, pos + 4)
        DP_STEP(alpha, a_sh[(pos + 5) & 1], wsb, fB1, pos + 5)
        DP_STEP(alpha, a_sh[(pos + 6) & 1], wsb, fB2, pos + 6)
        DP_STEP(alpha, a_sh[(pos + 7) & 1], wsb, fB3, pos + 7)
        fB0 = FLD(pos + 12); fB1 = FLD(pos + 13);
        fB2 = FLD(pos + 14); fB3 = FLD(pos + 15);
    }
    if (pos < len) { DP_STEP(alpha, a_sh[pos & 1], wsb, fA0, pos) ++pos; }
    if (pos < len) { DP_STEP(alpha, a_sh[pos & 1], wsb, fA1, pos) ++pos; }
    if (pos < len) { DP_STEP(alpha, a_sh[pos & 1], wsb, fA2, pos) ++pos; }
    if (pos < len) { DP_STEP(alpha, a_sh[pos & 1], wsb, fA3, pos) ++pos; }
    if (pos < len) { DP_STEP(alpha, a_sh[pos & 1], wsb, fB0, pos) ++pos; }
    if (pos < len) { DP_STEP(alpha, a_sh[pos & 1], wsb, fB1, pos) ++pos; }
    if (pos < len) { DP_STEP(alpha, a_sh[pos & 1], wsb, fB2, pos) ++pos; }
#undef FLD

    float v = alpha + trans[jc * TT + STOP_TAG];
    if (j >= NT) v = -3.0e38f;
    int idxb = j < NT ? j : 0;
    for (int off = 32; off; off >>= 1) {
        float vo = __shfl_xor(v, off, 64);
        int   io = __shfl_xor(idxb, off, 64);
        if (vo > v || (vo == v && io < idxb)) { v = vo; idxb = io; }
    }

    int ptr = idxb;
    int* ob = out + (size_t)b * SS;
    ob[len - 1] = ptr;

    const float* wsr = ws + ((size_t)b * SS) * 64;
    const float* fbase = feats + ((size_t)b * SS) * TT;

    float bvs[4], fs[4];
    float bvc = wsr[(size_t)(len - 1) * 64 + j];
#pragma unroll
    for (int k = 0; k < 4; ++k) {
        int r = len - 2 - k; int rc = r < 0 ? 0 : r;
        bvs[k] = wsr[(size_t)rc * 64 + j];
        fs[k]  = fbase[(size_t)rc * TT + jc];
    }

    int tpos = len - 1;
    while (tpos >= 4) {
        TB_STEP_G(ptr, tpos, bvc, bvs, fs, ob, wsr, fbase, 0)
        TB_STEP_G(ptr, tpos, bvc, bvs, fs, ob, wsr, fbase, 1)
        TB_STEP_G(ptr, tpos, bvc, bvs, fs, ob, wsr, fbase, 2)
        TB_STEP_G(ptr, tpos, bvc, bvs, fs, ob, wsr, fbase, 3)
    }
    if (tpos >= 1) TB_STEP_G(ptr, tpos, bvc, bvs, fs, ob, wsr, fbase, 0)
    if (tpos >= 1) TB_STEP_G(ptr, tpos, bvc, bvs, fs, ob, wsr, fbase, 1)
    if (tpos >= 1) TB_STEP_G(ptr, tpos, bvc, bvs, fs, ob, wsr, fbase, 2)

    for (int p = len + j; p < SS; p += 64) ob[p] = 0;
}

// ---------------- fallback (round-2 proven kernel, no workspace) ------------
__global__ __launch_bounds__(64, 1) void crf_viterbi(
    const float* __restrict__ feats,
    const void*  __restrict__ mask,
    const float* __restrict__ trans,
    int* __restrict__ out)
{
    __shared__ unsigned char bp_sh[SS * BPSTR];

    const int b = blockIdx.x;
    const int j = threadIdx.x;
    const int jc = j < NT ? j : NT - 1;

    const int len = seq_len(mask, b, j);

    float tt[NT];
#pragma unroll
    for (int i = 0; i < NT; ++i) tt[i] = trans[i * TT + j];

    const float* fp = feats + ((size_t)b * SS) * TT + jc;
    float alpha = trans[START_TAG * TT + jc] + fp[0];
    float fnext = fp[TT];

    for (int pos = 1; pos < len; ++pos) {
        const float f = fnext;
        { int np = pos + 1 < SS ? pos + 1 : SS - 1; fnext = fp[(size_t)np * TT]; }

        float best[4] = { -3.0e38f, -3.0e38f, -3.0e38f, -3.0e38f };
        int   bidx[4] = { 0, 0, 0, 0 };
        const int abits = __builtin_bit_cast(int, alpha);
#pragma unroll
        for (int i = 0; i < NT; ++i) {
            int ab = __builtin_amdgcn_readlane(abits, i);
            float s = __builtin_bit_cast(float, ab) + tt[i];
            const int c = i & 3;
            if (s > best[c]) { best[c] = s; bidx[c] = i; }
        }
        float bv = best[0]; int bi = bidx[0];
        if (best[1] > bv || (best[1] == bv && bidx[1] < bi)) { bv = best[1]; bi = bidx[1]; }
        if (best[2] > bv || (best[2] == bv && bidx[2] < bi)) { bv = best[2]; bi = bidx[2]; }
        if (best[3] > bv || (best[3] == bv && bidx[3] < bi)) { bv = best[3]; bi = bidx[3]; }

        alpha = bv + f;
        bp_sh[pos * BPSTR + j] = (unsigned char)bi;
    }

    float v = alpha + trans[jc * TT + STOP_TAG];
    if (j >= NT) v = -3.0e38f;
    int idx = j < NT ? j : 0;
    for (int off = 32; off; off >>= 1) {
        float vo = __shfl_xor(v, off, 64);
        int   io = __shfl_xor(idx, off, 64);
        if (vo > v || (vo == v && io < idx)) { v = vo; idx = io; }
    }

    __syncthreads();

    int ptr = idx;
    int* ob = out + (size_t)b * SS;
    for (int pos = len - 1; pos >= 1; --pos) {
        if (j == 0) ob[pos] = ptr;
        ptr = (int)bp_sh[pos * BPSTR + ptr];
    }
    if (j == 0) ob[0] = ptr;

    for (int p = len + j; p < SS; p += 64) ob[p] = 0;
}

extern "C" void kernel_launch(void* const* d_in, const int* in_sizes, int n_in,
                              void* d_out, int out_size, void* d_ws, size_t ws_size,
                              hipStream_t stream) {
    const float* feats = (const float*)d_in[0];
    const void*  mask  = d_in[1];
    // d_in[2] = tags, unused
    const float* trans = (const float*)d_in[3];
    int* out = (int*)d_out;

    const size_t need_bv = (size_t)BB * SS * 64 * sizeof(float);   // 128 MiB
    const size_t need_tot = need_bv + 2 * BB * sizeof(int);        // + lens + perm
    if (ws_size >= need_tot) {
        float* ws_bv = (float*)d_ws;
        int* lens_g = (int*)((char*)d_ws + need_bv);
        int* perm = lens_g + BB;
        crf_lens<<<dim3(BB), dim3(64), 0, stream>>>(mask, lens_g);
        crf_rank<<<dim3(1), dim3(1024), 0, stream>>>(lens_g, perm);
        crf_viterbi_fast2<<<dim3(BB / 2), dim3(64), 0, stream>>>(
            feats, trans, lens_g, perm, ws_bv, out);
    } else if (ws_size >= need_bv) {
        crf_viterbi_fast1<<<dim3(BB), dim3(64), 0, stream>>>(feats, mask, trans,
                                                             (float*)d_ws, out);
    } else {
        crf_viterbi<<<dim3(BB), dim3(64), 0, stream>>>(feats, mask, trans, out);
    }
}

// Round 11
// 180.348 us; speedup vs baseline: 1.8370x; 1.8370x over previous
//
#include <hip/hip_runtime.h>

#define TT 52          // tag count incl START/STOP
#define NT 50          // normal tags
#define START_TAG 50
#define STOP_TAG 51
#define BB 1024
#define SS 512
#define BPSTR 64       // fallback kernel LDS bp row stride

__device__ __forceinline__ int seq_len(const void* mask, int b, int j) {
    int cnt = 0;
    const unsigned* w = (const unsigned*)mask;
    unsigned w0 = w[0];
    unsigned w1 = w[1];
    if (w0 == 0x01010101u) {                       // bool / uint8
        const unsigned char* m = (const unsigned char*)mask + (size_t)b * SS;
        for (int k = j; k < SS; k += 64) cnt += (m[k] != 0);
    } else if (w0 == 0x3f800000u) {                // float32
        const float* m = (const float*)mask + (size_t)b * SS;
        for (int k = j; k < SS; k += 64) cnt += (m[k] != 0.f);
    } else if (w1 == 1u) {                         // int32
        const int* m = (const int*)mask + (size_t)b * SS;
        for (int k = j; k < SS; k += 64) cnt += (m[k] != 0);
    } else {                                       // int64
        const long long* m = (const long long*)mask + (size_t)b * SS;
        for (int k = j; k < SS; k += 64) cnt += (m[k] != 0);
    }
    for (int off = 32; off; off >>= 1) cnt += __shfl_xor(cnt, off, 64);
    return cnt > 0 ? cnt : 1;
}

__device__ __forceinline__ float4 add4(float4 a, float4 b) {
    return make_float4(a.x + b.x, a.y + b.y, a.z + b.z, a.w + b.w);
}
__device__ __forceinline__ float4 max4(float4 a, float4 b) {
    return make_float4(fmaxf(a.x, b.x), fmaxf(a.y, b.y),
                       fmaxf(a.z, b.z), fmaxf(a.w, b.w));
}

// One DP step (ambient: j, alpha, a_sh, A4, tt4, wsb):
// LDS broadcast (1 ds_write_b32 + 13 broadcast ds_read_b128), float4 lanewise
// add + max tree (packable to v_pk_*_f32), horizontal max, store bv,
// alpha = bv + f. Single LDS buffer: DS pipe executes a wave's ops in program
// order, so the next step's write cannot pass this step's reads (WAR safe).
// Exact max (order-independent) + identical per-element f32 adds => bv and
// alpha bit-identical to the reference scan.
#define DP_STEP(FREG, POSV)                                                       \
    {                                                                             \
        a_sh[j] = alpha;                                                          \
        float4 v0_ = add4(A4[0], tt4[0]);                                         \
        float4 v1_ = add4(A4[1], tt4[1]);                                         \
        float4 v2_ = add4(A4[2], tt4[2]);                                         \
        float4 v3_ = add4(A4[3], tt4[3]);                                         \
        float4 v4_ = add4(A4[4], tt4[4]);                                         \
        float4 v5_ = add4(A4[5], tt4[5]);                                         \
        float4 v6_ = add4(A4[6], tt4[6]);                                         \
        float4 v7_ = add4(A4[7], tt4[7]);                                         \
        float4 v8_ = add4(A4[8], tt4[8]);                                         \
        float4 v9_ = add4(A4[9], tt4[9]);                                         \
        float4 v10_ = add4(A4[10], tt4[10]);                                      \
        float4 v11_ = add4(A4[11], tt4[11]);                                      \
        float4 v12_ = add4(A4[12], tt4[12]);                                      \
        float4 m0_ = max4(v0_, v1_);                                              \
        float4 m1_ = max4(v2_, v3_);                                              \
        float4 m2_ = max4(v4_, v5_);                                              \
        float4 m3_ = max4(v6_, v7_);                                              \
        float4 m4_ = max4(v8_, v9_);                                              \
        float4 m5_ = max4(v10_, v11_);                                            \
        float4 p0_ = max4(m0_, m1_);                                              \
        float4 p1_ = max4(m2_, m3_);                                              \
        float4 p2_ = max4(m4_, m5_);                                              \
        float4 r0_ = max4(p0_, p1_);                                              \
        float4 r1_ = max4(p2_, v12_);                                             \
        float4 t_ = max4(r0_, r1_);                                               \
        float bv_ = fmaxf(fmaxf(t_.x, t_.y), fmaxf(t_.z, t_.w));                  \
        alpha = bv_ + (FREG);                                                     \
        wsb[(size_t)(POSV) * 64] = bv_;                                           \
    }

// generic value-match traceback step (ambient: j, jc, jr, trans_lds)
#define TB_STEP_G(PTR, TPOS, BVC, BVS, FS, OB, WSR, FB, K)                        \
    {                                                                             \
        float bvp_ = BVS[K];                                                      \
        float ap_ = bvp_ + FS[K];                                                 \
        float cand_ = ap_ + trans_lds[jr + PTR];                                  \
        float cm_ = (j < NT) ? cand_ : -3.0e38f;                                  \
        float tgt_ = __builtin_bit_cast(float,                                    \
            __builtin_amdgcn_readlane(__builtin_bit_cast(int, BVC), PTR));        \
        unsigned long long bm_ = __ballot(cm_ == tgt_);                           \
        PTR = __ffsll(bm_) - 1;                                                   \
        --TPOS;                                                                   \
        OB[TPOS] = PTR;                                                           \
        BVC = bvp_;                                                               \
        int rc_ = TPOS - 4; rc_ = rc_ < 0 ? 0 : rc_;                              \
        BVS[K] = WSR[(size_t)rc_ * 64 + j];                                       \
        FS[K] = FB[(size_t)rc_ * TT + jc];                                        \
    }

// ---------------- fast kernel: LDS-broadcast float4 fwd; value-match tb -----
__global__ __launch_bounds__(64, 1) void crf_viterbi_fast1(
    const float* __restrict__ feats,   // [B,S,T]
    const void*  __restrict__ mask,    // [B,S]
    const float* __restrict__ trans,   // [T,T]
    float* __restrict__ ws,            // [B,S,64] bv history (128 MiB)
    int* __restrict__ out)             // [B,S]
{
    __shared__ float trans_lds[64 * 53];            // [row i][col c], 53-padded
    __shared__ __align__(16) float a_sh[64];        // alpha broadcast (single buf)

    const int b = blockIdx.x;
    const int j = threadIdx.x;
    const int jc = j < NT ? j : NT - 1;
    const int jr = j * 53;
    const float4* A4 = (const float4*)a_sh;

    // stage trans rows into LDS (traceback use); rows >= NT get -inf sentinel
    for (int k = j; k < 64 * 53; k += 64) {
        int r = k / 53, c = k - r * 53;
        float v = -3.0e38f;
        if (r < NT && c < TT) v = trans[r * TT + c];
        trans_lds[k] = v;
    }

    const int len = seq_len(mask, b, j);

    // transition column trans[0..49][j] as 13 float4; mask slots 50,51
    float4 tt4[13];
#pragma unroll
    for (int r = 0; r < 13; ++r) {
        float c0 = trans[(4 * r + 0) * TT + j];
        float c1 = (4 * r + 1 < NT) ? trans[(4 * r + 1) * TT + j] : -3.0e38f;
        float c2 = (4 * r + 2 < NT) ? trans[(4 * r + 2) * TT + j] : -3.0e38f;
        float c3 = (4 * r + 3 < NT) ? trans[(4 * r + 3) * TT + j] : -3.0e38f;
        tt4[r] = make_float4(c0, c1, c2, c3);
    }

    // init (pos 0): alpha0 = bv0 + f0 with bv0 = trans[START][j]
    const float* fp = feats + ((size_t)b * SS) * TT + jc;
    float* wsb = ws + ((size_t)b * SS) * 64 + j;
    const float bvi = trans[START_TAG * TT + jc];
    float alpha = bvi + fp[0];
    wsb[0] = bvi;

#define FLD(P) fp[(size_t)((P) < SS ? (P) : SS - 1) * TT]
    // 8-deep feats prefetch; invariant at loop top:
    // fA = f[pos..pos+3], fB = f[pos+4..pos+7]
    float fA0 = FLD(1), fA1 = FLD(2), fA2 = FLD(3), fA3 = FLD(4);
    float fB0 = FLD(5), fB1 = FLD(6), fB2 = FLD(7), fB3 = FLD(8);

    int pos = 1;
    for (; pos + 7 < len; pos += 8) {
        DP_STEP(fA0, pos + 0)
        DP_STEP(fA1, pos + 1)
        DP_STEP(fA2, pos + 2)
        DP_STEP(fA3, pos + 3)
        fA0 = FLD(pos + 8);  fA1 = FLD(pos + 9);
        fA2 = FLD(pos + 10); fA3 = FLD(pos + 11);
        DP_STEP(fB0, pos + 4)
        DP_STEP(fB1, pos + 5)
        DP_STEP(fB2, pos + 6)
        DP_STEP(fB3, pos + 7)
        fB0 = FLD(pos + 12); fB1 = FLD(pos + 13);
        fB2 = FLD(pos + 14); fB3 = FLD(pos + 15);
    }
    // tail: fA = f[pos..pos+3], fB = f[pos+4..pos+7]; up to 7 steps remain
    if (pos < len) { DP_STEP(fA0, pos) ++pos; }
    if (pos < len) { DP_STEP(fA1, pos) ++pos; }
    if (pos < len) { DP_STEP(fA2, pos) ++pos; }
    if (pos < len) { DP_STEP(fA3, pos) ++pos; }
    if (pos < len) { DP_STEP(fB0, pos) ++pos; }
    if (pos < len) { DP_STEP(fB1, pos) ++pos; }
    if (pos < len) { DP_STEP(fB2, pos) ++pos; }
#undef FLD

    // ---- best last tag ----
    float v = alpha + trans[jc * TT + STOP_TAG];
    if (j >= NT) v = -3.0e38f;
    int idxb = j < NT ? j : 0;
    for (int off = 32; off; off >>= 1) {
        float vo = __shfl_xor(v, off, 64);
        int   io = __shfl_xor(idxb, off, 64);
        if (vo > v || (vo == v && io < idxb)) { v = vo; idxb = io; }
    }

    __syncthreads();   // trans_lds visibility (one-time, cheap)

    // ---- traceback by value matching ----
    int ptr = idxb;
    int* ob = out + (size_t)b * SS;
    ob[len - 1] = ptr;

    const float* wsr = ws + ((size_t)b * SS) * 64;        // + r*64 + j
    const float* fbase = feats + ((size_t)b * SS) * TT;   // + r*TT + jc

    float bvs[4], fs[4];
    float bvc = wsr[(size_t)(len - 1) * 64 + j];
#pragma unroll
    for (int k = 0; k < 4; ++k) {
        int r = len - 2 - k; int rc = r < 0 ? 0 : r;
        bvs[k] = wsr[(size_t)rc * 64 + j];
        fs[k]  = fbase[(size_t)rc * TT + jc];
    }

    int tpos = len - 1;
    while (tpos >= 4) {
        TB_STEP_G(ptr, tpos, bvc, bvs, fs, ob, wsr, fbase, 0)
        TB_STEP_G(ptr, tpos, bvc, bvs, fs, ob, wsr, fbase, 1)
        TB_STEP_G(ptr, tpos, bvc, bvs, fs, ob, wsr, fbase, 2)
        TB_STEP_G(ptr, tpos, bvc, bvs, fs, ob, wsr, fbase, 3)
    }
    if (tpos >= 1) TB_STEP_G(ptr, tpos, bvc, bvs, fs, ob, wsr, fbase, 0)
    if (tpos >= 1) TB_STEP_G(ptr, tpos, bvc, bvs, fs, ob, wsr, fbase, 1)
    if (tpos >= 1) TB_STEP_G(ptr, tpos, bvc, bvs, fs, ob, wsr, fbase, 2)

    // zero-fill positions >= len
    for (int p = len + j; p < SS; p += 64) ob[p] = 0;
}

// ---------------- fallback (round-2 proven kernel, no workspace) ------------
__global__ __launch_bounds__(64, 1) void crf_viterbi(
    const float* __restrict__ feats,
    const void*  __restrict__ mask,
    const float* __restrict__ trans,
    int* __restrict__ out)
{
    __shared__ unsigned char bp_sh[SS * BPSTR];

    const int b = blockIdx.x;
    const int j = threadIdx.x;
    const int jc = j < NT ? j : NT - 1;

    const int len = seq_len(mask, b, j);

    float tt[NT];
#pragma unroll
    for (int i = 0; i < NT; ++i) tt[i] = trans[i * TT + j];

    const float* fp = feats + ((size_t)b * SS) * TT + jc;
    float alpha = trans[START_TAG * TT + jc] + fp[0];
    float fnext = fp[TT];

    for (int pos = 1; pos < len; ++pos) {
        const float f = fnext;
        { int np = pos + 1 < SS ? pos + 1 : SS - 1; fnext = fp[(size_t)np * TT]; }

        float best[4] = { -3.0e38f, -3.0e38f, -3.0e38f, -3.0e38f };
        int   bidx[4] = { 0, 0, 0, 0 };
        const int abits = __builtin_bit_cast(int, alpha);
#pragma unroll
        for (int i = 0; i < NT; ++i) {
            int ab = __builtin_amdgcn_readlane(abits, i);
            float s = __builtin_bit_cast(float, ab) + tt[i];
            const int c = i & 3;
            if (s > best[c]) { best[c] = s; bidx[c] = i; }
        }
        float bv = best[0]; int bi = bidx[0];
        if (best[1] > bv || (best[1] == bv && bidx[1] < bi)) { bv = best[1]; bi = bidx[1]; }
        if (best[2] > bv || (best[2] == bv && bidx[2] < bi)) { bv = best[2]; bi = bidx[2]; }
        if (best[3] > bv || (best[3] == bv && bidx[3] < bi)) { bv = best[3]; bi = bidx[3]; }

        alpha = bv + f;
        bp_sh[pos * BPSTR + j] = (unsigned char)bi;
    }

    float v = alpha + trans[jc * TT + STOP_TAG];
    if (j >= NT) v = -3.0e38f;
    int idx = j < NT ? j : 0;
    for (int off = 32; off; off >>= 1) {
        float vo = __shfl_xor(v, off, 64);
        int   io = __shfl_xor(idx, off, 64);
        if (vo > v || (vo == v && io < idx)) { v = vo; idx = io; }
    }

    __syncthreads();

    int ptr = idx;
    int* ob = out + (size_t)b * SS;
    for (int pos = len - 1; pos >= 1; --pos) {
        if (j == 0) ob[pos] = ptr;
        ptr = (int)bp_sh[pos * BPSTR + ptr];
    }
    if (j == 0) ob[0] = ptr;

    for (int p = len + j; p < SS; p += 64) ob[p] = 0;
}

extern "C" void kernel_launch(void* const* d_in, const int* in_sizes, int n_in,
                              void* d_out, int out_size, void* d_ws, size_t ws_size,
                              hipStream_t stream) {
    const float* feats = (const float*)d_in[0];
    const void*  mask  = d_in[1];
    // d_in[2] = tags, unused
    const float* trans = (const float*)d_in[3];
    int* out = (int*)d_out;

    const size_t need = (size_t)BB * SS * 64 * sizeof(float);   // 128 MiB
    if (ws_size >= need) {
        crf_viterbi_fast1<<<dim3(BB), dim3(64), 0, stream>>>(feats, mask, trans,
                                                             (float*)d_ws, out);
    } else {
        crf_viterbi<<<dim3(BB), dim3(64), 0, stream>>>(feats, mask, trans, out);
    }
}